// Round 4
// baseline (3650.101 us; speedup 1.0000x reference)
//
#include <hip/hip_runtime.h>
#include <math.h>

#define SLEN 1024

__device__ __forceinline__ float sigf(float x) { return 1.0f / (1.0f + __expf(-x)); }

__device__ __forceinline__ float agent_ld(const float* p) {
  return __hip_atomic_load(p, __ATOMIC_RELAXED, __HIP_MEMORY_SCOPE_AGENT);
}
__device__ __forceinline__ void agent_st(float* p, float v) {
  __hip_atomic_store(p, v, __ATOMIC_RELAXED, __HIP_MEMORY_SCOPE_AGENT);
}
__device__ __forceinline__ bool is_sent(float f) { return __float_as_uint(f) == 0xFFFFFFFFu; }

// Defeat rematerialization: compiler must treat v as register-resident.
__device__ __forceinline__ void pin4(float4& v) {
  asm volatile("" : "+v"(v.x), "+v"(v.y), "+v"(v.z), "+v"(v.w));
}

// x[t, :] = emb[tokens[t, 63], :]   (only batch column 63 feeds h[:, T-1, :])
__global__ void embed_k(const int* __restrict__ tokens, const float* __restrict__ emb,
                        float* __restrict__ x) {
  const int t = blockIdx.x;
  const int tok = tokens[t * 64 + 63];
  const float4 v = ((const float4*)(emb + (size_t)tok * 512))[threadIdx.x];
  ((float4*)(x + (size_t)t * 512))[threadIdx.x] = v;
}

// One LSTM layer role, 256-thread blocks (4 waves), 1 block/CU.
// Wave w owns 2 hidden units {u0+2w, u0+2w+1}: 8 gate rows resident in VGPRs
// (~192 weight VGPRs/thread; __launch_bounds__(256,1) -> 512-VGPR budget so
// the allocator has no occupancy incentive to rematerialize the loads).
// Butterfly shuffle-reduce leaves ALL lanes with all 8 row sums; lanes 0/1
// compute the two cell updates in parallel. h gathered in LDS -> one
// coalesced 32B store per block (partial-line stores cost an HBM RMW).
template<int HOUT, int EIN, bool POLL_IN>
__device__ void lstm_role(int ublk,
                          const float* __restrict__ Wih, const float* __restrict__ Whh,
                          const float* __restrict__ bih, const float* __restrict__ bhh,
                          const float* __restrict__ in_hist, float* __restrict__ hout) {
  constexpr int C     = EIN + HOUT;
  constexpr int SLOTS = C / 256;        // float4 slots per lane
  constexpr int XQ    = EIN / 4;        // float4-index boundary Wih|Whh
  constexpr int EPN   = EIN / 256;      // input floats staged per thread
  constexpr int HPN   = HOUT / 256;     // h floats staged per thread (>=1)

  __shared__ __align__(16) float in_lds[2][C];
  __shared__ float h_g[8];

  const int tid = threadIdx.x;
  const int c   = tid & 63;
  const int w   = tid >> 6;             // wave index 0..3
  const int u0  = ublk * 8;

  // Persistent weight registers: rows r = j*4 + g (unit j in {0,1}, gate g)
  float4 wreg[8][SLOTS];
  #pragma unroll
  for (int j = 0; j < 2; ++j) {
    #pragma unroll
    for (int g = 0; g < 4; ++g) {
      const size_t grow = (size_t)g * HOUT + (size_t)(u0 + 2 * w + j);
      const float4* wih4 = (const float4*)(Wih + grow * EIN);
      const float4* whh4 = (const float4*)(Whh + grow * HOUT);
      #pragma unroll
      for (int s = 0; s < SLOTS; ++s) {
        const int c4 = s * 64 + c;
        wreg[j * 4 + g][s] = (c4 < XQ) ? wih4[c4] : whh4[c4 - XQ];
      }
    }
  }
  #pragma unroll
  for (int r = 0; r < 8; ++r)
    #pragma unroll
    for (int s = 0; s < SLOTS; ++s)
      pin4(wreg[r][s]);                 // force VGPR residency across the loop

  // Lane c in {0,1} owns unit u0+2w+c's bias + cell state
  float bg[4] = {0.f, 0.f, 0.f, 0.f};
  float cst = 0.f;
  if (c < 2) {
    const int u = u0 + 2 * w + c;
    #pragma unroll
    for (int g = 0; g < 4; ++g) bg[g] = bih[g * HOUT + u] + bhh[g * HOUT + u];
  }

  for (int t = 0; t < SLEN; ++t) {
    float ev[EPN];
    float hv[HPN];
    const float* esrc = in_hist + (size_t)t * EIN + EPN * tid;
    const float* hsrc = hout + (size_t)((t > 0 ? t : 1) - 1) * HOUT + HPN * tid;
    const bool hneed = (t > 0);

    if constexpr (POLL_IN) {
      for (;;) {
        bool ok = true;
        #pragma unroll
        for (int i = 0; i < EPN; ++i) ev[i] = agent_ld(esrc + i);
        if (hneed) {
          #pragma unroll
          for (int i = 0; i < HPN; ++i) hv[i] = agent_ld(hsrc + i);
          #pragma unroll
          for (int i = 0; i < HPN; ++i) ok &= !is_sent(hv[i]);
        }
        #pragma unroll
        for (int i = 0; i < EPN; ++i) ok &= !is_sent(ev[i]);
        if (ok) break;
        __builtin_amdgcn_s_sleep(1);
      }
    } else {
      #pragma unroll
      for (int i = 0; i < EPN; ++i) ev[i] = esrc[i];   // x: plain cached loads
      if (hneed) {
        for (;;) {
          bool ok = true;
          #pragma unroll
          for (int i = 0; i < HPN; ++i) hv[i] = agent_ld(hsrc + i);
          #pragma unroll
          for (int i = 0; i < HPN; ++i) ok &= !is_sent(hv[i]);
          if (ok) break;
          __builtin_amdgcn_s_sleep(1);
        }
      }
    }

    float* dst = in_lds[t & 1];
    #pragma unroll
    for (int i = 0; i < EPN; ++i) dst[EPN * tid + i] = ev[i];
    #pragma unroll
    for (int i = 0; i < HPN; ++i) dst[EIN + HPN * tid + i] = hneed ? hv[i] : 0.0f;
    __syncthreads();                    // barrier 1: in_lds ready

    float a[8];
    #pragma unroll
    for (int r = 0; r < 8; ++r) a[r] = 0.f;
    const float4* iv4 = (const float4*)dst;
    #pragma unroll
    for (int s = 0; s < SLOTS; ++s) {
      const float4 iv = iv4[s * 64 + c];
      #pragma unroll
      for (int r = 0; r < 8; ++r) {
        a[r] += wreg[r][s].x * iv.x + wreg[r][s].y * iv.y
              + wreg[r][s].z * iv.z + wreg[r][s].w * iv.w;
      }
    }
    #pragma unroll
    for (int off = 32; off > 0; off >>= 1)
      #pragma unroll
      for (int r = 0; r < 8; ++r) a[r] += __shfl_xor(a[r], off);

    if (c < 2) {                        // lane c computes unit u0+2w+c
      const float I = sigf(a[c * 4 + 0] + bg[0]);
      const float F = sigf(a[c * 4 + 1] + bg[1]);
      const float G = tanhf(a[c * 4 + 2] + bg[2]);
      const float O = sigf(a[c * 4 + 3] + bg[3]);
      cst = F * cst + I * G;
      h_g[2 * w + c] = O * tanhf(cst);
    }
    __syncthreads();                    // barrier 2: h_g ready
    if (tid < 8) {
      agent_st(hout + (size_t)t * HOUT + u0 + tid, h_g[tid]);  // one 32B txn
    }
  }
}

// out[t, :] = h2[t, :] @ Wlin.T + blin; 8 blocks, t strided by 8 (256 thr)
__device__ void final_role(int fb, const float* __restrict__ h2,
                           const float* __restrict__ Wlin, const float* __restrict__ blin,
                           float* __restrict__ out) {
  const int tid = threadIdx.x;
  float wl[7];
  #pragma unroll
  for (int o = 0; o < 7; ++o) wl[o] = Wlin[o * 256 + tid];
  __shared__ float red[4][7];
  for (int t = fb; t < SLEN; t += 8) {
    float h = agent_ld(h2 + (size_t)t * 256 + tid);
    while (is_sent(h)) {
      __builtin_amdgcn_s_sleep(1);
      h = agent_ld(h2 + (size_t)t * 256 + tid);
    }
    float p[7];
    #pragma unroll
    for (int o = 0; o < 7; ++o) p[o] = h * wl[o];
    #pragma unroll
    for (int off = 32; off > 0; off >>= 1) {
      #pragma unroll
      for (int o = 0; o < 7; ++o) p[o] += __shfl_xor(p[o], off);
    }
    const int w = tid >> 6;
    if ((tid & 63) == 0) {
      #pragma unroll
      for (int o = 0; o < 7; ++o) red[w][o] = p[o];
    }
    __syncthreads();
    if (tid == 0) {
      #pragma unroll
      for (int o = 0; o < 7; ++o)
        out[t * 7 + o] = red[0][o] + red[1][o] + red[2][o] + red[3][o] + blin[o];
    }
    __syncthreads();
  }
}

__global__ __launch_bounds__(256, 1) void pipe_k(
    const float* __restrict__ x,
    const float* __restrict__ Wih0, const float* __restrict__ Whh0,
    const float* __restrict__ bih0, const float* __restrict__ bhh0,
    const float* __restrict__ Wih1, const float* __restrict__ Whh1,
    const float* __restrict__ bih1, const float* __restrict__ bhh1,
    const float* __restrict__ Wih2, const float* __restrict__ Whh2,
    const float* __restrict__ bih2, const float* __restrict__ bhh2,
    const float* __restrict__ Wlin, const float* __restrict__ blin,
    float* __restrict__ h0, float* __restrict__ h1, float* __restrict__ h2,
    float* __restrict__ out) {
  const int b = blockIdx.x;
  if (b < 128) {
    lstm_role<1024, 512, false>(b, Wih0, Whh0, bih0, bhh0, x, h0);
  } else if (b < 192) {
    lstm_role<512, 1024, true>(b - 128, Wih1, Whh1, bih1, bhh1, h0, h1);
  } else if (b < 224) {
    lstm_role<256, 512, true>(b - 192, Wih2, Whh2, bih2, bhh2, h1, h2);
  } else {
    final_role(b - 224, h2, Wlin, blin, out);
  }
}

extern "C" void kernel_launch(void* const* d_in, const int* in_sizes, int n_in,
                              void* d_out, int out_size, void* d_ws, size_t ws_size,
                              hipStream_t stream) {
  const int*   tokens = (const int*)  d_in[0];
  const float* emb  = (const float*)d_in[1];
  const float* Wih0 = (const float*)d_in[2];
  const float* Whh0 = (const float*)d_in[3];
  const float* bih0 = (const float*)d_in[4];
  const float* bhh0 = (const float*)d_in[5];
  const float* Wih1 = (const float*)d_in[6];
  const float* Whh1 = (const float*)d_in[7];
  const float* bih1 = (const float*)d_in[8];
  const float* bhh1 = (const float*)d_in[9];
  const float* Wih2 = (const float*)d_in[10];
  const float* Whh2 = (const float*)d_in[11];
  const float* bih2 = (const float*)d_in[12];
  const float* bhh2 = (const float*)d_in[13];
  const float* Wlin = (const float*)d_in[14];
  const float* blin = (const float*)d_in[15];

  float* x  = (float*)d_ws;                      // 1024*512 f32 (2 MB)
  float* h0 = x  + (size_t)1024 * 512;           // 1024*1024 f32 (4 MB)
  float* h1 = h0 + (size_t)1024 * 1024;          // 1024*512  f32 (2 MB)
  float* h2 = h1 + (size_t)1024 * 512;           // 1024*256  f32 (1 MB)

  // Sentinel-fill the h history buffers (0xFFFFFFFF = NaN, never a valid h).
  hipMemsetAsync(h0, 0xFF,
                 ((size_t)1024*1024 + (size_t)1024*512 + (size_t)1024*256) * sizeof(float),
                 stream);
  embed_k<<<1024, 128, 0, stream>>>(tokens, emb, x);
  pipe_k<<<232, 256, 0, stream>>>(x, Wih0, Whh0, bih0, bhh0,
                                  Wih1, Whh1, bih1, bhh1,
                                  Wih2, Whh2, bih2, bhh2,
                                  Wlin, blin, h0, h1, h2, (float*)d_out);
}

// Round 5
// 3099.819 us; speedup vs baseline: 1.1775x; 1.1775x over previous
//
#include <hip/hip_runtime.h>
#include <math.h>

#define SLEN 1024

__device__ __forceinline__ float sigf(float x) { return 1.0f / (1.0f + __expf(-x)); }

__device__ __forceinline__ float agent_ld(const float* p) {
  return __hip_atomic_load(p, __ATOMIC_RELAXED, __HIP_MEMORY_SCOPE_AGENT);
}
__device__ __forceinline__ void agent_st(float* p, float v) {
  __hip_atomic_store(p, v, __ATOMIC_RELAXED, __HIP_MEMORY_SCOPE_AGENT);
}
__device__ __forceinline__ bool is_sent(float f) { return __float_as_uint(f) == 0xFFFFFFFFu; }

// Register-residency forcing: executed INSIDE the step loop, so the values
// must be in VGPRs every iteration -> spilling them to scratch would cost the
// allocator a per-iteration reload, which its own cost model rejects.
__device__ __forceinline__ void pin4(float4& v) {
  asm volatile("" : "+v"(v.x), "+v"(v.y), "+v"(v.z), "+v"(v.w));
}
#define DOT4(acc, wv, iv)                                                  \
  acc += (wv).x * (iv).x + (wv).y * (iv).y + (wv).z * (iv).z + (wv).w * (iv).w

// ---------------------------------------------------------------------------
// xg0_k: xg0[t][u][g] = Wih0[g*1024+u, :] . emb[tok_t, :] + bih0 + bhh0
// Fully parallel over t (input transform of layer 0 is not recurrent).
// 256 blocks x 512 thr: block = (t-parity, 8 units); wave = unit; lane c owns
// input cols [8c, 8c+8). Embedding gathered directly (x never materialized).
// ---------------------------------------------------------------------------
__global__ __launch_bounds__(512, 2) void xg0_k(const int* __restrict__ tokens,
                                                const float* __restrict__ emb,
                                                const float* __restrict__ Wih0,
                                                const float* __restrict__ bih0,
                                                const float* __restrict__ bhh0,
                                                float* __restrict__ xg0) {
  const int tid = threadIdx.x, c = tid & 63, w = tid >> 6;
  const int ublk = blockIdx.x & 127;        // which 8-unit slice
  const int tpar = blockIdx.x >> 7;         // t parity
  const int u = ublk * 8 + w;
  const float4* emb4 = (const float4*)emb;
  float4 wr[4][2];
  float bb[4];
  #pragma unroll
  for (int g = 0; g < 4; ++g) {
    const size_t row = (size_t)g * 1024 + u;
    const float4* w4 = (const float4*)(Wih0 + row * 512);
    wr[g][0] = w4[2 * c];
    wr[g][1] = w4[2 * c + 1];
    bb[g] = bih0[row] + bhh0[row];
  }
  float4* xg4 = (float4*)xg0;
  for (int t = tpar; t < SLEN; t += 2) {
    const int tok = tokens[t * 64 + 63];
    const float4 e0 = emb4[(size_t)tok * 128 + 2 * c];
    const float4 e1 = emb4[(size_t)tok * 128 + 2 * c + 1];
    float a[4] = {0.f, 0.f, 0.f, 0.f};
    #pragma unroll
    for (int g = 0; g < 4; ++g) { DOT4(a[g], wr[g][0], e0); DOT4(a[g], wr[g][1], e1); }
    #pragma unroll
    for (int off = 32; off > 0; off >>= 1)
      #pragma unroll
      for (int g = 0; g < 4; ++g) a[g] += __shfl_xor(a[g], off);
    if (c == 0)
      xg4[(size_t)t * 1024 + u] =
          make_float4(a[0] + bb[0], a[1] + bb[1], a[2] + bb[2], a[3] + bb[3]);
  }
}

// ---------------------------------------------------------------------------
// Layer-0 recurrent role: only Whh0 on the step path (xg0 precomputed).
// Wave w owns unit u: 4 gate rows x 1024 cols -> 16 float4/thread resident.
// ---------------------------------------------------------------------------
__device__ void l0_role(int ublk, const float* __restrict__ Whh,
                        const float* __restrict__ xg0, float* __restrict__ hout) {
  __shared__ __align__(16) float in_lds[2][1024];
  __shared__ float h_g[8];
  const int tid = threadIdx.x, c = tid & 63, w = tid >> 6;
  const int u0 = ublk * 8, u = u0 + w;

  float4 wreg[4][4];
  #pragma unroll
  for (int g = 0; g < 4; ++g) {
    const float4* whh4 = (const float4*)(Whh + ((size_t)g * 1024 + u) * 1024);
    #pragma unroll
    for (int s = 0; s < 4; ++s) wreg[g][s] = whh4[s * 64 + c];
  }
  const float4* xg4 = (const float4*)xg0;
  float cst = 0.f;

  for (int t = 0; t < SLEN; ++t) {
    #pragma unroll
    for (int g = 0; g < 4; ++g)
      #pragma unroll
      for (int s = 0; s < 4; ++s) pin4(wreg[g][s]);   // in-loop residency pin

    float4 xgv = make_float4(0.f, 0.f, 0.f, 0.f);
    if (c == 0) xgv = xg4[(size_t)t * 1024 + u];      // early, off the poll path

    float hv0 = 0.f, hv1 = 0.f;
    if (t > 0) {
      const float* hsrc = hout + (size_t)(t - 1) * 1024 + 2 * tid;
      for (;;) {
        hv0 = agent_ld(hsrc);
        hv1 = agent_ld(hsrc + 1);
        if (!is_sent(hv0) && !is_sent(hv1)) break;
        __builtin_amdgcn_s_sleep(1);
      }
    }
    float* dst = in_lds[t & 1];
    dst[2 * tid] = hv0;
    dst[2 * tid + 1] = hv1;
    __syncthreads();

    float a[4] = {0.f, 0.f, 0.f, 0.f};
    const float4* iv4 = (const float4*)dst;
    #pragma unroll
    for (int s = 0; s < 4; ++s) {
      const float4 iv = iv4[s * 64 + c];
      #pragma unroll
      for (int g = 0; g < 4; ++g) DOT4(a[g], wreg[g][s], iv);
    }
    #pragma unroll
    for (int off = 32; off > 0; off >>= 1)
      #pragma unroll
      for (int g = 0; g < 4; ++g) a[g] += __shfl_xor(a[g], off);

    if (c == 0) {
      const float I = sigf(a[0] + xgv.x);
      const float F = sigf(a[1] + xgv.y);
      const float G = tanhf(a[2] + xgv.z);
      const float O = sigf(a[3] + xgv.w);
      cst = F * cst + I * G;
      h_g[w] = O * tanhf(cst);
    }
    __syncthreads();
    if (tid < 8) agent_st(hout + (size_t)t * 1024 + u0 + tid, h_g[tid]);
  }
}

// ---------------------------------------------------------------------------
// Generic LSTM role (layers 1/2): full [Wih|Whh] on-path, wave owns unit.
// L1: 96 weight floats/thread; L2: 48. All under the v0-v255 window.
// ---------------------------------------------------------------------------
template<int HOUT, int EIN>
__device__ void lstm_role(int ublk,
                          const float* __restrict__ Wih, const float* __restrict__ Whh,
                          const float* __restrict__ bih, const float* __restrict__ bhh,
                          const float* __restrict__ in_hist, float* __restrict__ hout) {
  constexpr int C     = EIN + HOUT;
  constexpr int SLOTS = C / 256;
  constexpr int XQ    = EIN / 4;
  constexpr int EPN   = EIN / 512;
  constexpr int HPN   = 1;                 // HOUT <= 512 in these roles
  constexpr bool HGUARD = (HOUT < 512);

  __shared__ __align__(16) float in_lds[2][C];
  __shared__ float h_g[8];

  const int tid = threadIdx.x, c = tid & 63, w = tid >> 6;
  const int u0 = ublk * 8, u = u0 + w;

  float4 wreg[4][SLOTS];
  #pragma unroll
  for (int g = 0; g < 4; ++g) {
    const size_t grow = (size_t)g * HOUT + (size_t)u;
    const float4* wih4 = (const float4*)(Wih + grow * EIN);
    const float4* whh4 = (const float4*)(Whh + grow * HOUT);
    #pragma unroll
    for (int s = 0; s < SLOTS; ++s) {
      const int c4 = s * 64 + c;
      wreg[g][s] = (c4 < XQ) ? wih4[c4] : whh4[c4 - XQ];
    }
  }
  float bg[4] = {0.f, 0.f, 0.f, 0.f};
  float cst = 0.f;
  if (c == 0) {
    #pragma unroll
    for (int g = 0; g < 4; ++g) bg[g] = bih[g * HOUT + u] + bhh[g * HOUT + u];
  }

  for (int t = 0; t < SLEN; ++t) {
    #pragma unroll
    for (int g = 0; g < 4; ++g)
      #pragma unroll
      for (int s = 0; s < SLOTS; ++s) pin4(wreg[g][s]);  // in-loop residency pin

    float ev[EPN];
    float hv = 0.f;
    const float* esrc = in_hist + (size_t)t * EIN + EPN * tid;
    const float* hsrc = hout + (size_t)((t > 0 ? t : 1) - 1) * HOUT + tid;
    const bool hon   = (!HGUARD) || (tid < HOUT);
    const bool hneed = (t > 0) && hon;

    for (;;) {                              // combined poll: in + own h[t-1]
      bool ok = true;
      #pragma unroll
      for (int i = 0; i < EPN; ++i) ev[i] = agent_ld(esrc + i);
      if (hneed) { hv = agent_ld(hsrc); ok &= !is_sent(hv); }
      #pragma unroll
      for (int i = 0; i < EPN; ++i) ok &= !is_sent(ev[i]);
      if (ok) break;
      __builtin_amdgcn_s_sleep(1);
    }
    if (!hneed) hv = 0.f;

    float* dst = in_lds[t & 1];
    #pragma unroll
    for (int i = 0; i < EPN; ++i) dst[EPN * tid + i] = ev[i];
    if (hon) dst[EIN + tid] = hv;
    __syncthreads();

    float a[4] = {0.f, 0.f, 0.f, 0.f};
    const float4* iv4 = (const float4*)dst;
    #pragma unroll
    for (int s = 0; s < SLOTS; ++s) {
      const float4 iv = iv4[s * 64 + c];
      #pragma unroll
      for (int g = 0; g < 4; ++g) DOT4(a[g], wreg[g][s], iv);
    }
    #pragma unroll
    for (int off = 32; off > 0; off >>= 1)
      #pragma unroll
      for (int g = 0; g < 4; ++g) a[g] += __shfl_xor(a[g], off);

    if (c == 0) {
      const float I = sigf(a[0] + bg[0]);
      const float F = sigf(a[1] + bg[1]);
      const float G = tanhf(a[2] + bg[2]);
      const float O = sigf(a[3] + bg[3]);
      cst = F * cst + I * G;
      h_g[w] = O * tanhf(cst);
    }
    __syncthreads();
    if (tid < 8) agent_st(hout + (size_t)t * HOUT + u0 + tid, h_g[tid]);
  }
}

// out[t, :] = h2[t, :] @ Wlin.T + blin; 8 blocks, t strided by 8
__device__ void final_role(int fb, const float* __restrict__ h2,
                           const float* __restrict__ Wlin, const float* __restrict__ blin,
                           float* __restrict__ out) {
  const int tid = threadIdx.x;
  float wl[7];
  #pragma unroll
  for (int o = 0; o < 7; ++o) wl[o] = 0.f;
  if (tid < 256) {
    #pragma unroll
    for (int o = 0; o < 7; ++o) wl[o] = Wlin[o * 256 + tid];
  }
  __shared__ float red[4][7];
  for (int t = fb; t < SLEN; t += 8) {
    float h = 0.0f;
    if (tid < 256) {
      h = agent_ld(h2 + (size_t)t * 256 + tid);
      while (is_sent(h)) {
        __builtin_amdgcn_s_sleep(1);
        h = agent_ld(h2 + (size_t)t * 256 + tid);
      }
    }
    float p[7];
    #pragma unroll
    for (int o = 0; o < 7; ++o) p[o] = h * wl[o];
    #pragma unroll
    for (int off = 32; off > 0; off >>= 1) {
      #pragma unroll
      for (int o = 0; o < 7; ++o) p[o] += __shfl_xor(p[o], off);
    }
    const int w = tid >> 6;
    if (w < 4 && (tid & 63) == 0) {
      #pragma unroll
      for (int o = 0; o < 7; ++o) red[w][o] = p[o];
    }
    __syncthreads();
    if (tid == 0) {
      #pragma unroll
      for (int o = 0; o < 7; ++o)
        out[t * 7 + o] = red[0][o] + red[1][o] + red[2][o] + red[3][o] + blin[o];
    }
    __syncthreads();
  }
}

// 232 blocks x 512 thr, 1 block/CU. waves_per_eu(2,2): exactly 2 waves/EU ->
// 256-VGPR budget -> no occupancy incentive for the allocator to spill the
// persistent weight arrays.
__global__ __attribute__((amdgpu_flat_work_group_size(512, 512),
                          amdgpu_waves_per_eu(2, 2))) void pipe_k(
    const float* __restrict__ xg0,
    const float* __restrict__ Whh0,
    const float* __restrict__ Wih1, const float* __restrict__ Whh1,
    const float* __restrict__ bih1, const float* __restrict__ bhh1,
    const float* __restrict__ Wih2, const float* __restrict__ Whh2,
    const float* __restrict__ bih2, const float* __restrict__ bhh2,
    const float* __restrict__ Wlin, const float* __restrict__ blin,
    float* __restrict__ h0, float* __restrict__ h1, float* __restrict__ h2,
    float* __restrict__ out) {
  const int b = blockIdx.x;
  if (b < 128) {
    l0_role(b, Whh0, xg0, h0);
  } else if (b < 192) {
    lstm_role<512, 1024>(b - 128, Wih1, Whh1, bih1, bhh1, h0, h1);
  } else if (b < 224) {
    lstm_role<256, 512>(b - 192, Wih2, Whh2, bih2, bhh2, h1, h2);
  } else {
    final_role(b - 224, h2, Wlin, blin, out);
  }
}

extern "C" void kernel_launch(void* const* d_in, const int* in_sizes, int n_in,
                              void* d_out, int out_size, void* d_ws, size_t ws_size,
                              hipStream_t stream) {
  const int*   tokens = (const int*)  d_in[0];
  const float* emb  = (const float*)d_in[1];
  const float* Wih0 = (const float*)d_in[2];
  const float* Whh0 = (const float*)d_in[3];
  const float* bih0 = (const float*)d_in[4];
  const float* bhh0 = (const float*)d_in[5];
  const float* Wih1 = (const float*)d_in[6];
  const float* Whh1 = (const float*)d_in[7];
  const float* bih1 = (const float*)d_in[8];
  const float* bhh1 = (const float*)d_in[9];
  const float* Wih2 = (const float*)d_in[10];
  const float* Whh2 = (const float*)d_in[11];
  const float* bih2 = (const float*)d_in[12];
  const float* bhh2 = (const float*)d_in[13];
  const float* Wlin = (const float*)d_in[14];
  const float* blin = (const float*)d_in[15];

  float* xg0 = (float*)d_ws;                       // 1024*4096 f32 (16 MB)
  float* h0  = xg0 + (size_t)1024 * 4096;          // 1024*1024 f32 (4 MB)
  float* h1  = h0 + (size_t)1024 * 1024;           // 1024*512  f32 (2 MB)
  float* h2  = h1 + (size_t)1024 * 512;            // 1024*256  f32 (1 MB)

  // Sentinel-fill the h history buffers (0xFFFFFFFF = NaN, never a valid h).
  hipMemsetAsync(h0, 0xFF,
                 ((size_t)1024 * 1024 + (size_t)1024 * 512 + (size_t)1024 * 256) *
                     sizeof(float),
                 stream);
  xg0_k<<<256, 512, 0, stream>>>(tokens, emb, Wih0, bih0, bhh0, xg0);
  pipe_k<<<232, 512, 0, stream>>>(xg0, Whh0,
                                  Wih1, Whh1, bih1, bhh1,
                                  Wih2, Whh2, bih2, bhh2,
                                  Wlin, blin, h0, h1, h2, (float*)d_out);
}

// Round 6
// 2947.292 us; speedup vs baseline: 1.2385x; 1.0518x over previous
//
#include <hip/hip_runtime.h>
#include <math.h>

#define SLEN 1024

__device__ __forceinline__ float sigf(float x) { return 1.0f / (1.0f + __expf(-x)); }

__device__ __forceinline__ float agent_ld(const float* p) {
  return __hip_atomic_load(p, __ATOMIC_RELAXED, __HIP_MEMORY_SCOPE_AGENT);
}
__device__ __forceinline__ void agent_st(float* p, float v) {
  __hip_atomic_store(p, v, __ATOMIC_RELAXED, __HIP_MEMORY_SCOPE_AGENT);
}
__device__ __forceinline__ bool is_sent(float f) { return __float_as_uint(f) == 0xFFFFFFFFu; }

// In-loop register pin: values must be in VGPRs at the asm each iteration, so
// spilling them costs the allocator a per-iteration reload (rejected by its
// own cost model for <=64 floats/thread — empirically verified R5).
__device__ __forceinline__ void pin4(float4& v) {
  asm volatile("" : "+v"(v.x), "+v"(v.y), "+v"(v.z), "+v"(v.w));
}
#define DOT4(acc, wv, iv)                                                  \
  acc += (wv).x * (iv).x + (wv).y * (iv).y + (wv).z * (iv).z + (wv).w * (iv).w

// ---------------------------------------------------------------------------
// xg0_k: xg0[t][u][g] = Wih0[g*1024+u, :] . emb[tok_t, :] + bih0 + bhh0
// 1024 blocks x 512 thr: block = (t-phase 0..7, 8-unit slice); wave = unit.
// ---------------------------------------------------------------------------
__global__ __launch_bounds__(512, 2) void xg0_k(const int* __restrict__ tokens,
                                                const float* __restrict__ emb,
                                                const float* __restrict__ Wih0,
                                                const float* __restrict__ bih0,
                                                const float* __restrict__ bhh0,
                                                float* __restrict__ xg0) {
  const int tid = threadIdx.x, c = tid & 63, w = tid >> 6;
  const int ublk = blockIdx.x & 127;        // which 8-unit slice
  const int tph  = blockIdx.x >> 7;         // t phase 0..7
  const int u = ublk * 8 + w;
  const float4* emb4 = (const float4*)emb;
  float4 wr[4][2];
  float bb[4];
  #pragma unroll
  for (int g = 0; g < 4; ++g) {
    const size_t row = (size_t)g * 1024 + u;
    const float4* w4 = (const float4*)(Wih0 + row * 512);
    wr[g][0] = w4[2 * c];
    wr[g][1] = w4[2 * c + 1];
    bb[g] = bih0[row] + bhh0[row];
  }
  float4* xg4 = (float4*)xg0;
  for (int t = tph; t < SLEN; t += 8) {
    const int tok = tokens[t * 64 + 63];
    const float4 e0 = emb4[(size_t)tok * 128 + 2 * c];
    const float4 e1 = emb4[(size_t)tok * 128 + 2 * c + 1];
    float a[4] = {0.f, 0.f, 0.f, 0.f};
    #pragma unroll
    for (int g = 0; g < 4; ++g) { DOT4(a[g], wr[g][0], e0); DOT4(a[g], wr[g][1], e1); }
    #pragma unroll
    for (int off = 32; off > 0; off >>= 1)
      #pragma unroll
      for (int g = 0; g < 4; ++g) a[g] += __shfl_xor(a[g], off);
    if (c == 0)
      xg4[(size_t)t * 1024 + u] =
          make_float4(a[0] + bb[0], a[1] + bb[1], a[2] + bb[2], a[3] + bb[3]);
  }
}

// ---------------------------------------------------------------------------
// Layer-0 recurrent role: Whh0 only (xg0 precomputed). Wave w owns unit u:
// 16 float4/thread ALL register-resident (<=64 floats: RA-safe per R5).
// Dynamic blob used only for in_lds + h gather.
// ---------------------------------------------------------------------------
__device__ void l0_role(int ublk, char* blob, const float* __restrict__ Whh,
                        const float* __restrict__ xg0, float* __restrict__ hout) {
  float* in_base = (float*)blob;            // [2][1024]
  float* hg = in_base + 2 * 1024;           // [8]
  const int tid = threadIdx.x, c = tid & 63, w = tid >> 6;
  const int u0 = ublk * 8, u = u0 + w;

  float4 wreg[4][4];
  #pragma unroll
  for (int g = 0; g < 4; ++g) {
    const float4* whh4 = (const float4*)(Whh + ((size_t)g * 1024 + u) * 1024);
    #pragma unroll
    for (int s = 0; s < 4; ++s) wreg[g][s] = whh4[s * 64 + c];
  }
  const float4* xg4 = (const float4*)xg0;
  float cst = 0.f;

  for (int t = 0; t < SLEN; ++t) {
    #pragma unroll
    for (int g = 0; g < 4; ++g)
      #pragma unroll
      for (int s = 0; s < 4; ++s) pin4(wreg[g][s]);

    float4 xgv = make_float4(0.f, 0.f, 0.f, 0.f);
    if (c == 0) xgv = xg4[(size_t)t * 1024 + u];     // latency overlaps poll

    float hv0 = 0.f, hv1 = 0.f;
    if (t > 0) {
      const float* hsrc = hout + (size_t)(t - 1) * 1024 + 2 * tid;
      for (;;) {
        hv0 = agent_ld(hsrc);
        hv1 = agent_ld(hsrc + 1);
        if (!is_sent(hv0) && !is_sent(hv1)) break;
      }
    }
    float* dst = in_base + (t & 1) * 1024;
    dst[2 * tid] = hv0;
    dst[2 * tid + 1] = hv1;
    __syncthreads();

    float a[4] = {0.f, 0.f, 0.f, 0.f};
    const float4* iv4 = (const float4*)dst;
    #pragma unroll
    for (int s = 0; s < 4; ++s) {
      const float4 iv = iv4[s * 64 + c];
      #pragma unroll
      for (int g = 0; g < 4; ++g) DOT4(a[g], wreg[g][s], iv);
    }
    #pragma unroll
    for (int off = 32; off > 0; off >>= 1)
      #pragma unroll
      for (int g = 0; g < 4; ++g) a[g] += __shfl_xor(a[g], off);

    if (c == 0) {
      const float I = sigf(a[0] + xgv.x);
      const float F = sigf(a[1] + xgv.y);
      const float G = tanhf(a[2] + xgv.z);
      const float O = sigf(a[3] + xgv.w);
      cst = F * cst + I * G;
      hg[w] = O * tanhf(cst);
    }
    __syncthreads();
    if (tid < 8) agent_st(hout + (size_t)t * 1024 + u0 + tid, hg[tid]);
  }
}

// ---------------------------------------------------------------------------
// Generic role: RSLOTS weight slots in registers (16 floats each, <=48 total:
// RA-safe), remaining SLOTS-RSLOTS slots in DYNAMIC LDS (deterministic
// residency; replaces the per-step L2 weight re-stream).
// LDS layout: wlds4[(sl*32 + (w*4+g))*64 + c]; lanes contiguous -> conflict-
// free ds_read_b128. Then [2][C] in_lds, then 8-float h gather.
// ---------------------------------------------------------------------------
template<int HOUT, int EIN, int RSLOTS>
__device__ void lstm_role(int ublk, char* blob,
                          const float* __restrict__ Wih, const float* __restrict__ Whh,
                          const float* __restrict__ bih, const float* __restrict__ bhh,
                          const float* __restrict__ in_hist, float* __restrict__ hout) {
  constexpr int C      = EIN + HOUT;
  constexpr int SLOTS  = C / 256;
  constexpr int LSLOTS = SLOTS - RSLOTS;
  constexpr int XQ     = EIN / 4;
  constexpr int EPN    = EIN / 512;
  constexpr bool HGUARD = (HOUT < 512);

  float4* wlds4  = (float4*)blob;
  float* in_base = (float*)blob + (size_t)LSLOTS * 32 * 64 * 4;
  float* hg      = in_base + 2 * C;

  const int tid = threadIdx.x, c = tid & 63, w = tid >> 6;
  const int u0 = ublk * 8, u = u0 + w;

  // Fill LDS weight slots (coalesced: consecutive tid -> consecutive float4)
  for (int k = tid; k < LSLOTS * 32 * 64; k += 512) {
    const int cc = k & 63, rr = k >> 6, r = rr & 31, sl = rr >> 5;
    const int g = r & 3, wu = r >> 2;
    const size_t grow = (size_t)g * HOUT + (size_t)(u0 + wu);
    const float4* wih4 = (const float4*)(Wih + grow * EIN);
    const float4* whh4 = (const float4*)(Whh + grow * HOUT);
    const int c4 = (RSLOTS + sl) * 64 + cc;
    wlds4[k] = (c4 < XQ) ? wih4[c4] : whh4[c4 - XQ];
  }

  // Register weight slots
  float4 wreg[4][RSLOTS];
  #pragma unroll
  for (int g = 0; g < 4; ++g) {
    const size_t grow = (size_t)g * HOUT + (size_t)u;
    const float4* wih4 = (const float4*)(Wih + grow * EIN);
    const float4* whh4 = (const float4*)(Whh + grow * HOUT);
    #pragma unroll
    for (int s = 0; s < RSLOTS; ++s) {
      const int c4 = s * 64 + c;
      wreg[g][s] = (c4 < XQ) ? wih4[c4] : whh4[c4 - XQ];
    }
  }
  float bg[4] = {0.f, 0.f, 0.f, 0.f};
  float cst = 0.f;
  if (c == 0) {
    #pragma unroll
    for (int g = 0; g < 4; ++g) bg[g] = bih[g * HOUT + u] + bhh[g * HOUT + u];
  }

  for (int t = 0; t < SLEN; ++t) {
    #pragma unroll
    for (int g = 0; g < 4; ++g)
      #pragma unroll
      for (int s = 0; s < RSLOTS; ++s) pin4(wreg[g][s]);

    float ev[EPN];
    float hv = 0.f;
    const float* esrc = in_hist + (size_t)t * EIN + EPN * tid;
    const float* hsrc = hout + (size_t)((t > 0 ? t : 1) - 1) * HOUT + tid;
    const bool hon   = (!HGUARD) || (tid < HOUT);
    const bool hneed = (t > 0) && hon;

    for (;;) {                              // combined poll: in + h[t-1]
      bool ok = true;
      #pragma unroll
      for (int i = 0; i < EPN; ++i) ev[i] = agent_ld(esrc + i);
      if (hneed) { hv = agent_ld(hsrc); ok &= !is_sent(hv); }
      #pragma unroll
      for (int i = 0; i < EPN; ++i) ok &= !is_sent(ev[i]);
      if (ok) break;
    }
    if (!hneed) hv = 0.f;

    float* dst = in_base + (t & 1) * C;
    #pragma unroll
    for (int i = 0; i < EPN; ++i) dst[EPN * tid + i] = ev[i];
    if (hon) dst[EIN + tid] = hv;
    __syncthreads();

    float a[4] = {0.f, 0.f, 0.f, 0.f};
    const float4* iv4 = (const float4*)dst;
    #pragma unroll
    for (int s = 0; s < RSLOTS; ++s) {
      const float4 iv = iv4[s * 64 + c];
      #pragma unroll
      for (int g = 0; g < 4; ++g) DOT4(a[g], wreg[g][s], iv);
    }
    #pragma unroll
    for (int sl = 0; sl < LSLOTS; ++sl) {
      const float4 iv = iv4[(RSLOTS + sl) * 64 + c];
      #pragma unroll
      for (int g = 0; g < 4; ++g) {
        const float4 wv = wlds4[((sl * 32) + (w * 4 + g)) * 64 + c];
        DOT4(a[g], wv, iv);
      }
    }
    #pragma unroll
    for (int off = 32; off > 0; off >>= 1)
      #pragma unroll
      for (int g = 0; g < 4; ++g) a[g] += __shfl_xor(a[g], off);

    if (c == 0) {
      const float I = sigf(a[0] + bg[0]);
      const float F = sigf(a[1] + bg[1]);
      const float G = tanhf(a[2] + bg[2]);
      const float O = sigf(a[3] + bg[3]);
      cst = F * cst + I * G;
      hg[w] = O * tanhf(cst);
    }
    __syncthreads();
    if (tid < 8) agent_st(hout + (size_t)t * HOUT + u0 + tid, hg[tid]);
  }
}

// out[t, :] = h2[t, :] @ Wlin.T + blin; 8 blocks, t strided by 8
__device__ void final_role(int fb, const float* __restrict__ h2,
                           const float* __restrict__ Wlin, const float* __restrict__ blin,
                           float* __restrict__ out) {
  const int tid = threadIdx.x;
  float wl[7];
  #pragma unroll
  for (int o = 0; o < 7; ++o) wl[o] = 0.f;
  if (tid < 256) {
    #pragma unroll
    for (int o = 0; o < 7; ++o) wl[o] = Wlin[o * 256 + tid];
  }
  __shared__ float red[4][7];
  for (int t = fb; t < SLEN; t += 8) {
    float h = 0.0f;
    if (tid < 256) {
      h = agent_ld(h2 + (size_t)t * 256 + tid);
      while (is_sent(h)) h = agent_ld(h2 + (size_t)t * 256 + tid);
    }
    float p[7];
    #pragma unroll
    for (int o = 0; o < 7; ++o) p[o] = h * wl[o];
    #pragma unroll
    for (int off = 32; off > 0; off >>= 1) {
      #pragma unroll
      for (int o = 0; o < 7; ++o) p[o] += __shfl_xor(p[o], off);
    }
    const int w = tid >> 6;
    if (w < 4 && (tid & 63) == 0) {
      #pragma unroll
      for (int o = 0; o < 7; ++o) red[w][o] = p[o];
    }
    __syncthreads();
    if (tid == 0) {
      #pragma unroll
      for (int o = 0; o < 7; ++o)
        out[t * 7 + o] = red[0][o] + red[1][o] + red[2][o] + red[3][o] + blin[o];
    }
    __syncthreads();
  }
}

// Dynamic-LDS bytes: L1 role is the max user:
//   3 slots * 32 rows * 64 float4 * 16B = 98304
// + in_lds 2*1536*4 = 12288, + h gather 8*4 = 32  -> 110624
#define PIPE_DYN_LDS 110624

__global__ __attribute__((amdgpu_flat_work_group_size(512, 512),
                          amdgpu_waves_per_eu(2, 2))) void pipe_k(
    const float* __restrict__ xg0,
    const float* __restrict__ Whh0,
    const float* __restrict__ Wih1, const float* __restrict__ Whh1,
    const float* __restrict__ bih1, const float* __restrict__ bhh1,
    const float* __restrict__ Wih2, const float* __restrict__ Whh2,
    const float* __restrict__ bih2, const float* __restrict__ bhh2,
    const float* __restrict__ Wlin, const float* __restrict__ blin,
    float* __restrict__ h0, float* __restrict__ h1, float* __restrict__ h2,
    float* __restrict__ out) {
  extern __shared__ float4 dyn4[];
  char* blob = (char*)dyn4;
  const int b = blockIdx.x;
  if (b < 128) {
    l0_role(b, blob, Whh0, xg0, h0);
  } else if (b < 192) {
    lstm_role<512, 1024, 3>(b - 128, blob, Wih1, Whh1, bih1, bhh1, h0, h1);
  } else if (b < 224) {
    lstm_role<256, 512, 3>(b - 192, blob, Wih2, Whh2, bih2, bhh2, h1, h2);
  } else {
    final_role(b - 224, h2, Wlin, blin, out);
  }
}

extern "C" void kernel_launch(void* const* d_in, const int* in_sizes, int n_in,
                              void* d_out, int out_size, void* d_ws, size_t ws_size,
                              hipStream_t stream) {
  const int*   tokens = (const int*)  d_in[0];
  const float* emb  = (const float*)d_in[1];
  const float* Wih0 = (const float*)d_in[2];
  const float* Whh0 = (const float*)d_in[3];
  const float* bih0 = (const float*)d_in[4];
  const float* bhh0 = (const float*)d_in[5];
  const float* Wih1 = (const float*)d_in[6];
  const float* Whh1 = (const float*)d_in[7];
  const float* bih1 = (const float*)d_in[8];
  const float* bhh1 = (const float*)d_in[9];
  const float* Wih2 = (const float*)d_in[10];
  const float* Whh2 = (const float*)d_in[11];
  const float* bih2 = (const float*)d_in[12];
  const float* bhh2 = (const float*)d_in[13];
  const float* Wlin = (const float*)d_in[14];
  const float* blin = (const float*)d_in[15];

  float* xg0 = (float*)d_ws;                       // 1024*4096 f32 (16 MB)
  float* h0  = xg0 + (size_t)1024 * 4096;          // 1024*1024 f32 (4 MB)
  float* h1  = h0 + (size_t)1024 * 1024;           // 1024*512  f32 (2 MB)
  float* h2  = h1 + (size_t)1024 * 512;            // 1024*256  f32 (1 MB)

  // Allow >64KB dynamic LDS (host-side attr set; no stream interaction, so
  // graph-capture-safe; idempotent and deterministic).
  (void)hipFuncSetAttribute((const void*)pipe_k,
                            hipFuncAttributeMaxDynamicSharedMemorySize,
                            PIPE_DYN_LDS);

  // Sentinel-fill the h history buffers (0xFFFFFFFF = NaN, never a valid h).
  hipMemsetAsync(h0, 0xFF,
                 ((size_t)1024 * 1024 + (size_t)1024 * 512 + (size_t)1024 * 256) *
                     sizeof(float),
                 stream);
  xg0_k<<<1024, 512, 0, stream>>>(tokens, emb, Wih0, bih0, bhh0, xg0);
  pipe_k<<<232, 512, PIPE_DYN_LDS, stream>>>(xg0, Whh0,
                                             Wih1, Whh1, bih1, bhh1,
                                             Wih2, Whh2, bih2, bhh2,
                                             Wlin, blin, h0, h1, h2, (float*)d_out);
}